// Round 1
// 71.538 us; speedup vs baseline: 1.0385x; 1.0385x over previous
//
#include <hip/hip_runtime.h>

typedef float f2 __attribute__((ext_vector_type(2)));

namespace {
constexpr int kB = 4;
constexpr int kN = 4096;             // points per set per batch (N == M)
constexpr int kPts = kB * kN;        // per set = 16384
constexpr int kP = 2 * kPts;         // all per-point mins = 32768
constexpr int kBlk = 256;
constexpr int kSplit = 16;           // blocks splitting the inner scan
constexpr int kChunk = kN / kSplit;  // 256 other-points per block
constexpr int kOP = 2;               // own points per thread
constexpr float kInf = 3.4e38f;
}

// ws layout: [keys: kP u32][pack: kP float4 worth of pair-interleaved floats]
// Pair-interleaved pack: for point pair g, float4 pack4[2g] = {x0,x1,y0,y1},
// pack4[2g+1] = {z0,z1,w0,w1}, w = ||p||^2. Pairs [0, kPts/2) = target set,
// [kPts/2, kP/2) = source set. This layout puts v_pk_fma_f32 operands in
// adjacent registers after the wave-uniform s_load_dwordx4.

// Monotone float<->uint map: unsigned atomicMin orders all floats (partial
// e = ||y||^2 - 2 x.y can be negative).
__device__ __forceinline__ unsigned enc(float f) {
  unsigned u = __float_as_uint(f);
  return (u & 0x80000000u) ? ~u : (u | 0x80000000u);
}
__device__ __forceinline__ float dec(unsigned k) {
  return __uint_as_float((k & 0x80000000u) ? (k ^ 0x80000000u) : ~k);
}

// One thread per point PAIR: contiguous 24B read, two float4 stores, one
// uint2 key-init. Pairs never straddle the set boundary (kPts even).
__global__ __launch_bounds__(kBlk) void cham_prep_kernel(
    const float* __restrict__ src, const float* __restrict__ tgt,
    float4* __restrict__ pack4, unsigned* __restrict__ keys,
    float* __restrict__ out) {
  int g = blockIdx.x * kBlk + threadIdx.x;  // pair id, grid covers kP/2
  const float* p = (g < kPts / 2) ? (tgt + (size_t)g * 6)
                                  : (src + (size_t)(g - kPts / 2) * 6);
  const f2 a = *(const f2*)(p);      // {x0, y0}   (8B-aligned: 24g % 8 == 0)
  const f2 bv = *(const f2*)(p + 2); // {z0, x1}
  const f2 c = *(const f2*)(p + 4);  // {y1, z1}
  const float x0 = a.x, y0 = a.y, z0 = bv.x;
  const float x1 = bv.y, y1 = c.x, z1 = c.y;
  const float w0 = fmaf(x0, x0, fmaf(y0, y0, z0 * z0));
  const float w1 = fmaf(x1, x1, fmaf(y1, y1, z1 * z1));
  pack4[2 * g] = make_float4(x0, x1, y0, y1);
  pack4[2 * g + 1] = make_float4(z0, z1, w0, w1);
  ((uint2*)keys)[g] = make_uint2(0xFFFFFFFFu, 0xFFFFFFFFu);  // +max for atomicMin
  if (g == 0) out[0] = 0.0f;
}

// One thread = kOP(=2) own points (read from pack4, w precomputed); scans a
// 256-point chunk of the other set via wave-uniform s_load of pack4.
// min||x-y||^2 = ||x||^2 + min(||y||^2 - 2 x.y). Inner 2-point group:
// 2 wave-uniform s_load_dwordx4 + shared W SGPR->VGPR copy + per own
// {3 v_pk_fma (W folded into chain tail) + 1 v_min3}  => ~2.25 VALU/pair,
// 2x fewer scalar loads/waits per pair than 1-own, two independent min
// chains per own (g&1 ping-pong) for ILP.
// NO fences / fused reduce (R3: per-wave __threadfence cost ~100 us).
__global__ __launch_bounds__(kBlk) void cham_min_kernel(
    const float4* __restrict__ pack4, unsigned* __restrict__ keys) {
  const int dir = blockIdx.z;  // 0: s->t (other = tgt = first half), 1: t->s
  const int b = blockIdx.y;
  const int chunk = blockIdx.x & (kSplit - 1);
  const int ntile = blockIdx.x >> 4;  // kSplit == 16
  const int tp = ntile * kBlk + threadIdx.x;  // own PAIR index within (dir,b)

  // own set: dir==0 -> src (second half of pack), dir==1 -> tgt (first half)
  const size_t ownPair =
      ((size_t)(1 - dir) * kPts + (size_t)b * kN) / 2 + (size_t)tp;
  const float4 OA = pack4[2 * ownPair];      // {x0, x1, y0, y1}
  const float4 OB = pack4[2 * ownPair + 1];  // {z0, z1, w0, w1}
  const f2 NX0 = {-2.0f * OA.x, -2.0f * OA.x};
  const f2 NY0 = {-2.0f * OA.z, -2.0f * OA.z};
  const f2 NZ0 = {-2.0f * OB.x, -2.0f * OB.x};
  const f2 NX1 = {-2.0f * OA.y, -2.0f * OA.y};
  const f2 NY1 = {-2.0f * OA.w, -2.0f * OA.w};
  const f2 NZ1 = {-2.0f * OB.y, -2.0f * OB.y};

  // other-set chunk start, in 2-point groups (2 float4s per group)
  const size_t g0 =
      ((size_t)dir * kPts + (size_t)b * kN + (size_t)chunk * kChunk) / 2;
  const float4* __restrict__ q = pack4 + 2 * g0;

  float e0a = kInf, e0b = kInf, e1a = kInf, e1b = kInf;
#pragma unroll 8
  for (int g = 0; g < kChunk / 2; ++g) {
    const float4 A = q[2 * g + 0];   // {x0, x1, y0, y1}
    const float4 Bv = q[2 * g + 1];  // {z0, z1, w0, w1}
    const f2 X = {A.x, A.y}, Y = {A.z, A.w}, Z = {Bv.x, Bv.y};
    f2 Wv = {Bv.z, Bv.w};  // single SGPR->VGPR materialization, shared
    f2 d0 = __builtin_elementwise_fma(
        NX0, X,
        __builtin_elementwise_fma(NY0, Y,
                                  __builtin_elementwise_fma(NZ0, Z, Wv)));
    f2 d1 = __builtin_elementwise_fma(
        NX1, X,
        __builtin_elementwise_fma(NY1, Y,
                                  __builtin_elementwise_fma(NZ1, Z, Wv)));
    if (g & 1) {  // statically resolved under unroll (8k+j -> j&1)
      e0b = fminf(fminf(d0.x, d0.y), e0b);  // v_min3
      e1b = fminf(fminf(d1.x, d1.y), e1b);
    } else {
      e0a = fminf(fminf(d0.x, d0.y), e0a);
      e1a = fminf(fminf(d1.x, d1.y), e1a);
    }
  }

  const float best0 = fminf(e0a, e0b) + OB.z;  // + ||own0||^2
  const float best1 = fminf(e1a, e1b) + OB.w;  // + ||own1||^2
  const unsigned kbase = ((unsigned)(dir * kB + b)) * kN + 2u * (unsigned)tp;
  atomicMin(&keys[kbase + 0], enc(best0));
  atomicMin(&keys[kbase + 1], enc(best1));
}

// Decode keys, sum all 2*B*N per-point mins, scale by 1/(B*N) (N == M).
__global__ __launch_bounds__(kBlk) void cham_reduce_kernel(
    const unsigned* __restrict__ keys, float* __restrict__ out) {
  __shared__ float red[kBlk];
  float acc = 0.0f;
  for (int i = blockIdx.x * kBlk + threadIdx.x; i < kP; i += gridDim.x * kBlk)
    acc += dec(keys[i]);
  red[threadIdx.x] = acc;
  __syncthreads();
  for (int s = kBlk / 2; s > 0; s >>= 1) {
    if (threadIdx.x < s) red[threadIdx.x] += red[threadIdx.x + s];
    __syncthreads();
  }
  if (threadIdx.x == 0) atomicAdd(out, red[0] * (1.0f / kPts));
}

extern "C" void kernel_launch(void* const* d_in, const int* in_sizes, int n_in,
                              void* d_out, int out_size, void* d_ws,
                              size_t ws_size, hipStream_t stream) {
  const float* src = (const float*)d_in[0];  // (B, N, 3) fp32
  const float* tgt = (const float*)d_in[1];  // (B, M, 3) fp32
  float* out = (float*)d_out;                // scalar fp32

  unsigned* keys = (unsigned*)d_ws;                       // 128 KB
  float* packf = (float*)((char*)d_ws + (size_t)kP * 4);  // 512 KB, 16B-align

  cham_prep_kernel<<<dim3(kP / 2 / kBlk), kBlk, 0, stream>>>(
      src, tgt, (float4*)packf, keys, out);

  // (8 own-pair tiles * 16 splits, B, 2 dirs) = 1024 blocks -> 4/CU,
  // 16 waves/CU; atomic count unchanged vs 1-own (2 per thread).
  dim3 grid(kN / (kBlk * kOP) * kSplit, kB, 2);
  cham_min_kernel<<<grid, kBlk, 0, stream>>>((const float4*)packf, keys);

  cham_reduce_kernel<<<dim3(16), kBlk, 0, stream>>>(keys, out);
}